// Round 3
// baseline (326.229 us; speedup 1.0000x reference)
//
#include <hip/hip_runtime.h>

typedef _Float16 half8 __attribute__((ext_vector_type(8)));
typedef _Float16 half4 __attribute__((ext_vector_type(4)));
typedef float    f32x4 __attribute__((ext_vector_type(4)));

#define T_TOK 16384
#define D_DIM 4096
#define E_EXP 128
#define CAP   256
#define BM    64
#define NT    128   // K-steps of 32

// ---------------------------------------------------------------------------
// Kernel 0: wg (fp32) -> scaled split-fp16 planes. w64 = wg*64 (exact pow2
// rescale keeps w_m in fp16 normal range); h = fp16(w64), m = fp16(w64 - h).
// ---------------------------------------------------------------------------
__global__ __launch_bounds__(256) void prep_wg(
    const float* __restrict__ wg, _Float16* __restrict__ wh,
    _Float16* __restrict__ wm)
{
    const int i = (blockIdx.x * 256 + threadIdx.x) * 4;
    const f32x4 v = *reinterpret_cast<const f32x4*>(wg + i);
    half4 h, m;
#pragma unroll
    for (int j = 0; j < 4; j++) {
        const float s = v[j] * 64.0f;
        const _Float16 hh = (_Float16)s;
        h[j] = hh;
        m[j] = (_Float16)(s - (float)hh);
    }
    *reinterpret_cast<half4*>(wh + i) = h;
    *reinterpret_cast<half4*>(wm + i) = m;
}

// ---------------------------------------------------------------------------
// Kernel A: barrier-free split-fp16 MFMA GEMM, fragments loaded straight from
// global (A: x fp32 -> in-reg split; B: fp16 planes, L2-resident).
// 512 thr = 8 waves (2 row-groups x 4 col-groups), wave tile 32x32.
// LDS only for the logits epilogue.
// ---------------------------------------------------------------------------
__global__ __launch_bounds__(512, 2) void gemm_gate(
    const float* __restrict__ x, const _Float16* __restrict__ wh,
    const _Float16* __restrict__ wm, float* __restrict__ out,
    float* __restrict__ me)
{
    __shared__ float lg[BM][E_EXP + 1];

    const int tid  = threadIdx.x;
    const int row0 = blockIdx.x * BM;
    const int lane = tid & 63;
    const int wid  = tid >> 6;
    const int wrow = wid >> 2;   // 0..1
    const int wcol = wid & 3;    // 0..3
    const int lr   = lane & 15;
    const int lq   = lane >> 4;  // k-span: halfs [lq*8, lq*8+8)

    // A fragment sources: rows (row0 + 32*wrow + 16*rf + lr), k offset lq*8
    const float* xp0 = x + (size_t)(row0 + 32 * wrow + lr) * D_DIM + lq * 8;
    const float* xp1 = xp0 + 16 * D_DIM;
    // B fragment sources: cols (32*wcol + 16*cf + lr)
    const size_t boff = (size_t)(32 * wcol + lr) * D_DIM + lq * 8;
    const _Float16* b0h = wh + boff;
    const _Float16* b1h = b0h + 16 * D_DIM;
    const _Float16* b0m = wm + boff;
    const _Float16* b1m = b0m + 16 * D_DIM;

    f32x4 acc[2][2];
#pragma unroll
    for (int i = 0; i < 2; i++)
#pragma unroll
        for (int j = 0; j < 2; j++) acc[i][j] = (f32x4)0.0f;

#define LOAD_A(dst, k)                                                        \
    {                                                                         \
        dst[0][0] = *reinterpret_cast<const f32x4*>(xp0 + (k));               \
        dst[0][1] = *reinterpret_cast<const f32x4*>(xp0 + (k) + 4);           \
        dst[1][0] = *reinterpret_cast<const f32x4*>(xp1 + (k));               \
        dst[1][1] = *reinterpret_cast<const f32x4*>(xp1 + (k) + 4);           \
    }
#define LOAD_B(dh, dm, k)                                                     \
    {                                                                         \
        dh[0] = *reinterpret_cast<const half8*>(b0h + (k));                   \
        dh[1] = *reinterpret_cast<const half8*>(b1h + (k));                   \
        dm[0] = *reinterpret_cast<const half8*>(b0m + (k));                   \
        dm[1] = *reinterpret_cast<const half8*>(b1m + (k));                   \
    }
#define COMPUTE(xa, bh, bm)                                                   \
    {                                                                         \
        half8 Ah[2], Am[2];                                                   \
        _Pragma("unroll") for (int rf = 0; rf < 2; rf++)                      \
            _Pragma("unroll") for (int j = 0; j < 8; j++)                     \
        {                                                                     \
            const float s = xa[rf][j >> 2][j & 3];                            \
            const _Float16 hh = (_Float16)s;                                  \
            Ah[rf][j] = hh;                                                   \
            Am[rf][j] = (_Float16)(s - (float)hh);                            \
        }                                                                     \
        _Pragma("unroll") for (int rf = 0; rf < 2; rf++)                      \
            _Pragma("unroll") for (int cf = 0; cf < 2; cf++)                  \
        {                                                                     \
            acc[rf][cf] = __builtin_amdgcn_mfma_f32_16x16x32_f16(             \
                Am[rf], bm[cf], acc[rf][cf], 0, 0, 0);                        \
            acc[rf][cf] = __builtin_amdgcn_mfma_f32_16x16x32_f16(             \
                Am[rf], bh[cf], acc[rf][cf], 0, 0, 0);                        \
            acc[rf][cf] = __builtin_amdgcn_mfma_f32_16x16x32_f16(             \
                Ah[rf], bm[cf], acc[rf][cf], 0, 0, 0);                        \
            acc[rf][cf] = __builtin_amdgcn_mfma_f32_16x16x32_f16(             \
                Ah[rf], bh[cf], acc[rf][cf], 0, 0, 0);                        \
        }                                                                     \
    }

    f32x4 a0[2][2], a1[2][2];
    half8 bh0[2], bm0[2], bh1[2], bm1[2];

    LOAD_A(a0, 0);
    LOAD_B(bh0, bm0, 0);

    for (int t = 0; t < NT; t += 2) {
        const int k1 = ((t + 1) & (NT - 1)) * 32;   // wraps harmlessly at end
        LOAD_A(a1, k1);
        LOAD_B(bh1, bm1, k1);
        COMPUTE(a0, bh0, bm0);

        const int k2 = ((t + 2) & (NT - 1)) * 32;
        LOAD_A(a0, k2);
        LOAD_B(bh0, bm0, k2);
        COMPUTE(a1, bh1, bm1);
    }

#undef LOAD_A
#undef LOAD_B
#undef COMPUTE

    // ---- epilogue: logits -> LDS, scale by 1/64 ----
#pragma unroll
    for (int rf = 0; rf < 2; rf++)
#pragma unroll
        for (int cf = 0; cf < 2; cf++)
#pragma unroll
            for (int r = 0; r < 4; r++) {
                const int row = 32 * wrow + 16 * rf + lq * 4 + r;
                const int col = 32 * wcol + 16 * cf + lr;
                lg[row][col] = acc[rf][cf][r] * 0.015625f;
            }
    __syncthreads();

    if (tid < BM) {
        const int r = tid;
        const int t = row0 + r;
        float m1 = -1e30f, m2 = -1e30f;
        int   i1 = 0, i2 = 0;
        for (int e = 0; e < E_EXP; e++) {
            const float v = lg[r][e];
            if (v > m1)      { m2 = m1; i2 = i1; m1 = v; i1 = e; }
            else if (v > m2) { m2 = v; i2 = e; }
        }
        float s = 0.0f;
        for (int e = 0; e < E_EXP; e++) s += __expf(lg[r][e] - m1);
        const float inv = 1.0f / s;

        out[3 + 0 * T_TOK + t] = (float)i1;
        out[3 + 1 * T_TOK + t] = (float)i2;
        out[3 + 4 * T_TOK + t] = inv;
        out[3 + 5 * T_TOK + t] = __expf(m2 - m1) * inv;

        for (int e = 0; e < E_EXP; e++)
            lg[r][e] = __expf(lg[r][e] - m1) * inv;
    }
    __syncthreads();

    if (tid < E_EXP) {
        float s = 0.0f;
        for (int r = 0; r < BM; r++) s += lg[r][tid];
        atomicAdd(&me[tid], s);
    }
}

// ---------------------------------------------------------------------------
// Kernel B: per-expert rank (cumsum) for locations1_s / locations2_s + ce.
// ---------------------------------------------------------------------------
__global__ __launch_bounds__(256) void rank_kernel(
    float* __restrict__ out, float* __restrict__ ce)
{
    const int e    = blockIdx.x;
    const int tid  = threadIdx.x;
    const int lane = tid & 63;
    const int w    = tid >> 6;

    __shared__ int wtot[4];

    const float* idx1 = out + 3;
    const float* idx2 = out + 3 + T_TOK;
    float* loc1 = out + 3 + 2 * T_TOK;
    float* loc2 = out + 3 + 3 * T_TOK;

    const unsigned long long below = (1ull << lane) - 1ull;
    int base = 0;

    for (int t0 = 0; t0 < T_TOK; t0 += 256) {
        const int t = t0 + tid;
        const int f = ((int)idx1[t] == e);
        const unsigned long long m = __ballot(f);
        const int pre = __popcll(m & below);
        const int tot = __popcll(m);
        if (lane == 0) wtot[w] = tot;
        __syncthreads();
        int off = 0;
        for (int i = 0; i < w; i++) off += wtot[i];
        const int all = wtot[0] + wtot[1] + wtot[2] + wtot[3];
        if (f) {
            const int rank = base + off + pre;
            loc1[t] = (rank < CAP) ? (float)rank : 0.0f;
        }
        base += all;
        __syncthreads();
    }

    const int count1 = base;
    if (tid == 0) ce[e] = (float)((count1 < CAP) ? count1 : CAP);

    for (int t0 = 0; t0 < T_TOK; t0 += 256) {
        const int t = t0 + tid;
        const int f = ((int)idx2[t] == e);
        const unsigned long long m = __ballot(f);
        const int pre = __popcll(m & below);
        const int tot = __popcll(m);
        if (lane == 0) wtot[w] = tot;
        __syncthreads();
        int off = 0;
        for (int i = 0; i < w; i++) off += wtot[i];
        const int all = wtot[0] + wtot[1] + wtot[2] + wtot[3];
        if (f) {
            const int rank = base + off + pre;
            loc2[t] = (rank < CAP) ? (float)rank : 0.0f;
        }
        base += all;
        __syncthreads();
    }
}

// ---------------------------------------------------------------------------
// Kernel C: l_aux = sum(me*ce) * E/(T*T); plus capacity and E constants.
// ---------------------------------------------------------------------------
__global__ __launch_bounds__(128) void finalize_kernel(
    const float* __restrict__ me, const float* __restrict__ ce,
    float* __restrict__ out)
{
    __shared__ float red[2];
    const int tid = threadIdx.x;
    float p = me[tid] * ce[tid];
#pragma unroll
    for (int o = 32; o > 0; o >>= 1) p += __shfl_down(p, o);
    if ((tid & 63) == 0) red[tid >> 6] = p;
    __syncthreads();
    if (tid == 0) {
        const float tot = red[0] + red[1];
        out[0] = tot * ((float)E_EXP / ((float)T_TOK * (float)T_TOK));
        out[1] = (float)CAP;
        out[2] = (float)E_EXP;
    }
}

extern "C" void kernel_launch(void* const* d_in, const int* in_sizes, int n_in,
                              void* d_out, int out_size, void* d_ws, size_t ws_size,
                              hipStream_t stream)
{
    const float* x  = (const float*)d_in[0];
    const float* wg = (const float*)d_in[1];
    float* out = (float*)d_out;

    float* me = (float*)d_ws;            // 128 floats
    float* ce = me + 128;                // 128 floats
    _Float16* wh = (_Float16*)((char*)d_ws + 1024);            // 1 MB
    _Float16* wm = wh + (size_t)E_EXP * D_DIM;                 // 1 MB

    hipMemsetAsync(me, 0, 128 * sizeof(float), stream);
    prep_wg<<<(E_EXP * D_DIM) / (256 * 4), 256, 0, stream>>>(wg, wh, wm);
    gemm_gate<<<T_TOK / BM, 512, 0, stream>>>(x, wh, wm, out, me);
    rank_kernel<<<E_EXP, 256, 0, stream>>>(out, ce);
    finalize_kernel<<<1, 128, 0, stream>>>(me, ce, out);
}